// Round 3
// baseline (1434.789 us; speedup 1.0000x reference)
//
#include <hip/hip_runtime.h>
#include <stdint.h>

#define N_NODES 100000
#define N_EDGES 320000
#define DIM 256
#define BN_EPS 1e-5f

typedef __attribute__((ext_vector_type(8))) short short8;
typedef __attribute__((ext_vector_type(4))) float f32x4;

__device__ __forceinline__ float bf2f(unsigned short u) {
    union { unsigned int i; float f; } v; v.i = ((unsigned int)u) << 16; return v.f;
}
__device__ __forceinline__ unsigned short f2bf(float f) {
    union { float f; unsigned int i; } v; v.f = f;
    unsigned int x = v.i;
    return (unsigned short)((x + 0x7fffu + ((x >> 16) & 1u)) >> 16);  // RNE
}

// edge_index accessor: handles int32 or int64 (little-endian low word) storage
__device__ __forceinline__ int eidx(const int* ei, int i64, int which, int e) {
    int idx = which * N_EDGES + e;
    return i64 ? ei[idx * 2] : ei[idx];
}

// ---- runtime dtype detection ----
// flags[0]=1 if x is fp32 (else bf16); flags[1]=1 if W is fp32; flags[2]=1 if edge_index is int64
__global__ void k_detect(const unsigned short* __restrict__ xs,
                         const unsigned short* __restrict__ wsw,
                         const int* __restrict__ ei, int* __restrict__ flags) {
    __shared__ int red[3];
    int tid = threadIdx.x;
    if (tid < 3) red[tid] = 0;
    __syncthreads();
    int badx = 0, badw = 0, nz = 0;
    for (int j = 0; j < 8; ++j) {
        float vx = bf2f(xs[tid * 8 + j]);
        if (!(fabsf(vx) <= 1000.0f)) badx = 1;   // catches huge AND NaN
        float vw = bf2f(wsw[tid * 8 + j]);
        if (!(fabsf(vw) <= 1000.0f)) badw = 1;
        if (ei[(tid * 8 + j) * 2 + 1] != 0) nz = 1;  // odd words nonzero => int32
    }
    if (badx) atomicOr(&red[0], 1);
    if (badw) atomicOr(&red[1], 1);
    if (nz)   atomicOr(&red[2], 1);
    __syncthreads();
    if (tid == 0) { flags[0] = red[0]; flags[1] = red[1]; flags[2] = red[2] ? 0 : 1; }
}

// ---- deg init (self-loop = 1.0) + zero BN stats ----
__global__ void k_init(float* __restrict__ deg, float* __restrict__ stats) {
    int i = blockIdx.x * 256 + threadIdx.x;
    if (i < N_NODES) deg[i] = 1.0f;
    if (i < 512) stats[i] = 0.0f;
}

__global__ void k_deg(const int* __restrict__ ei, float* __restrict__ deg,
                      const int* __restrict__ flags) {
    int i64 = flags[2];
    int e = blockIdx.x * 256 + threadIdx.x;
    if (e < N_EDGES) atomicAdd(&deg[eidx(ei, i64, 1, e)], 1.0f);
}

__global__ void k_dinv(const float* __restrict__ deg, float* __restrict__ dinv) {
    int i = blockIdx.x * 256 + threadIdx.x;
    if (i < N_NODES) dinv[i] = rsqrtf(deg[i]);
}

// ---- W -> transposed split-bf16 (hi + lo) ----
__global__ void k_wt(const void* __restrict__ wv, unsigned short* __restrict__ Wth,
                     unsigned short* __restrict__ Wtl, const int* __restrict__ flags) {
    int wf32 = flags[1];
    int k = blockIdx.x, n = threadIdx.x;
    float v = wf32 ? ((const float*)wv)[k * DIM + n]
                   : bf2f(((const unsigned short*)wv)[k * DIM + n]);
    unsigned short h = f2bf(v);
    float lo = v - bf2f(h);
    Wth[(size_t)n * DIM + k] = h;
    Wtl[(size_t)n * DIM + k] = f2bf(lo);    // 0 when W was bf16
}

// ---- z init (self-loop term): z[node][:] = dinv^2 * x[node][:]  (fp32) ----
__global__ void k_zinit(const void* __restrict__ xv, const float* __restrict__ dinv,
                        float* __restrict__ z, const int* __restrict__ flags, int base) {
    int xf32 = flags[0];
    int t = blockIdx.x * 256 + threadIdx.x;     // count*64 threads
    int node = base + (t >> 6);
    float dv = dinv[node];
    float s = dv * dv;
    size_t goff = (size_t)node * DIM + (size_t)(t & 63) * 4;
    f32x4 o;
    if (xf32) {
        f32x4 v = *(const f32x4*)((const float*)xv + goff);
        o[0] = v[0] * s; o[1] = v[1] * s; o[2] = v[2] * s; o[3] = v[3] * s;
    } else {
        uint2 u = *(const uint2*)((const unsigned short*)xv + goff);
        o[0] = bf2f((unsigned short)(u.x & 0xffffu)) * s;
        o[1] = bf2f((unsigned short)(u.x >> 16)) * s;
        o[2] = bf2f((unsigned short)(u.y & 0xffffu)) * s;
        o[3] = bf2f((unsigned short)(u.y >> 16)) * s;
    }
    *(f32x4*)(z + (size_t)t * 4) = o;
}

// ---- edge scatter: one wave per edge, lane handles 4 features; rows [base,base+count) ----
__global__ void k_scatter(const void* __restrict__ xv, const int* __restrict__ ei,
                          const float* __restrict__ dinv, float* __restrict__ z,
                          const int* __restrict__ flags, int base, int count) {
    int xf32 = flags[0];
    int i64 = flags[2];
    int gid = blockIdx.x * 256 + threadIdx.x;
    int e = gid >> 6;
    int lane = gid & 63;
    int c = eidx(ei, i64, 1, e);
    int cl = c - base;
    if ((unsigned)cl >= (unsigned)count) return;   // wave-uniform predicate
    int r = eidx(ei, i64, 0, e);
    float norm = dinv[r] * dinv[c];
    float v0, v1, v2, v3;
    size_t xo = (size_t)r * DIM + (size_t)(lane * 4);
    if (xf32) {
        f32x4 t = *(const f32x4*)((const float*)xv + xo);
        v0 = t[0]; v1 = t[1]; v2 = t[2]; v3 = t[3];
    } else {
        uint2 u = *(const uint2*)((const unsigned short*)xv + xo);
        v0 = bf2f((unsigned short)(u.x & 0xffffu));
        v1 = bf2f((unsigned short)(u.x >> 16));
        v2 = bf2f((unsigned short)(u.y & 0xffffu));
        v3 = bf2f((unsigned short)(u.y >> 16));
    }
    float* zp = z + (size_t)cl * DIM + (size_t)(lane * 4);
    atomicAdd(zp + 0, v0 * norm);
    atomicAdd(zp + 1, v1 * norm);
    atomicAdd(zp + 2, v2 * norm);
    atomicAdd(zp + 3, v3 * norm);
}

// ---- GEMM: out[base+..] = z_local @ W, split-bf16 (3 MFMAs), M-tile=80; fp32 output ----
__launch_bounds__(256)
__global__ void k_gemm(const float* __restrict__ z, const unsigned short* __restrict__ Wth,
                       const unsigned short* __restrict__ Wtl, float* __restrict__ out,
                       int base) {
    __shared__ unsigned short zh[80][264];   // +8 pad: breaks b128 bank conflicts
    __shared__ unsigned short zl[80][264];
    int tid = threadIdx.x;
    int m0l = blockIdx.x * 80;
    int rr = tid >> 4;
    int c0 = (tid & 15) * 16;
    #pragma unroll
    for (int p = 0; p < 5; ++p) {
        int r = p * 16 + rr;
        const float* src = z + (size_t)(m0l + r) * DIM + c0;
        #pragma unroll
        for (int half = 0; half < 2; ++half) {
            short8 ph, pl;
            #pragma unroll
            for (int j4 = 0; j4 < 8; j4 += 4) {
                f32x4 t = *(const f32x4*)(src + half * 8 + j4);
                #pragma unroll
                for (int j = 0; j < 4; ++j) {
                    float v = t[j];
                    unsigned short h = f2bf(v);
                    ph[j4 + j] = (short)h;
                    pl[j4 + j] = (short)f2bf(v - bf2f(h));
                }
            }
            *(short8*)&zh[r][c0 + half * 8] = ph;
            *(short8*)&zl[r][c0 + half * 8] = pl;
        }
    }
    __syncthreads();
    int w = tid >> 6, lane = tid & 63, quad = lane >> 4, rl = lane & 15;
    f32x4 acc[5][4];
    #pragma unroll
    for (int ms = 0; ms < 5; ++ms)
        #pragma unroll
        for (int nt = 0; nt < 4; ++nt)
            acc[ms][nt] = (f32x4){0.f, 0.f, 0.f, 0.f};
    #pragma unroll
    for (int kk = 0; kk < 8; ++kk) {
        int k0 = kk * 32 + quad * 8;
        short8 bh[4], bl[4];
        #pragma unroll
        for (int nt = 0; nt < 4; ++nt) {
            int n = w * 64 + nt * 16 + rl;
            bh[nt] = *(const short8*)(Wth + (size_t)n * DIM + k0);
            bl[nt] = *(const short8*)(Wtl + (size_t)n * DIM + k0);
        }
        #pragma unroll
        for (int ms = 0; ms < 5; ++ms) {
            short8 ah = *(const short8*)&zh[ms * 16 + rl][k0];
            short8 al = *(const short8*)&zl[ms * 16 + rl][k0];
            #pragma unroll
            for (int nt = 0; nt < 4; ++nt) {
                acc[ms][nt] = __builtin_amdgcn_mfma_f32_16x16x32_bf16(ah, bh[nt], acc[ms][nt], 0, 0, 0);
                acc[ms][nt] = __builtin_amdgcn_mfma_f32_16x16x32_bf16(al, bh[nt], acc[ms][nt], 0, 0, 0);
                acc[ms][nt] = __builtin_amdgcn_mfma_f32_16x16x32_bf16(ah, bl[nt], acc[ms][nt], 0, 0, 0);
            }
        }
    }
    // C/D layout: col = lane&15 (n), row = quad*4 + reg (m); fp32 stores
    #pragma unroll
    for (int ms = 0; ms < 5; ++ms)
        #pragma unroll
        for (int nt = 0; nt < 4; ++nt)
            #pragma unroll
            for (int i = 0; i < 4; ++i) {
                int gr = base + m0l + ms * 16 + quad * 4 + i;
                out[(size_t)gr * DIM + w * 64 + nt * 16 + rl] = acc[ms][nt][i];
            }
}

// ---- BN stats: per-column sum & sumsq over nodes (fp32 out0) ----
__global__ void k_stats(const float* __restrict__ out, float* __restrict__ stats) {
    int f = threadIdx.x;
    int r0 = blockIdx.x * 100;
    float s1 = 0.f, s2 = 0.f;
    const float* p = out + (size_t)r0 * DIM + f;
    for (int j = 0; j < 100; ++j) {
        float v = p[(size_t)j * DIM];
        s1 += v; s2 += v * v;
    }
    atomicAdd(&stats[f], s1);
    atomicAdd(&stats[256 + f], s2);
}

// ---- fold BN into per-column scale/shift ----
__global__ void k_fin(const float* __restrict__ stats, const void* __restrict__ gv,
                      const void* __restrict__ bv, float* __restrict__ scsh,
                      const int* __restrict__ flags) {
    int ff32 = flags[0];   // gamma/beta assumed same dtype as x
    int f = threadIdx.x;
    const float invN = 1.0f / (float)N_NODES;
    float mean = stats[f] * invN;
    float var = stats[256 + f] * invN - mean * mean;
    float g = ff32 ? ((const float*)gv)[f] : bf2f(((const unsigned short*)gv)[f]);
    float bb = ff32 ? ((const float*)bv)[f] : bf2f(((const unsigned short*)bv)[f]);
    float sc = g * rsqrtf(var + BN_EPS);
    scsh[f] = sc;
    scsh[256 + f] = bb - mean * sc;
}

// ---- fused normalize + tanh, in place on fp32 d_out ----
__global__ void k_final(float* __restrict__ out, const float* __restrict__ scsh) {
    int t = blockIdx.x * 256 + threadIdx.x;   // N*64 threads
    int f0 = (t & 63) * 4;
    size_t off = (size_t)t * 4;
    f32x4 v = *(const f32x4*)(out + off);
    f32x4 o;
    #pragma unroll
    for (int j = 0; j < 4; ++j)
        o[j] = tanhf(v[j] * scsh[f0 + j] + scsh[256 + f0 + j]);
    *(f32x4*)(out + off) = o;
}

extern "C" void kernel_launch(void* const* d_in, const int* in_sizes, int n_in,
                              void* d_out, int out_size, void* d_ws, size_t ws_size,
                              hipStream_t stream) {
    const void* x     = d_in[0];
    const void* W     = d_in[1];
    // d_in[2] = b: per-column additive constant -> cancelled exactly by BatchNorm. Unused.
    const void* gamma = d_in[3];
    const void* beta  = d_in[4];
    const int* ei     = (const int*)d_in[5];
    float* out = (float*)d_out;                      // fp32 output (round-2 evidence: 2.0078125 packing signature)

    char* ws = (char*)d_ws;
    int*   flags = (int*)(ws);                       // 64 B
    float* deg   = (float*)(ws + 1024);              // 400 KB
    float* dinv  = (float*)(ws + 524288);            // 400 KB
    float* stats = (float*)(ws + 1048576);           // 2 KB
    float* scsh  = (float*)(ws + 1052672);           // 2 KB
    unsigned short* Wth = (unsigned short*)(ws + 1056768);  // 128 KB
    unsigned short* Wtl = (unsigned short*)(ws + 1187840);  // 128 KB
    float* z     = (float*)(ws + 2097152);           // up to 102.4 MB (chunked if ws small)

    size_t zbytes = ws_size > 2097152 ? ws_size - 2097152 : 0;
    long long maxRows = (long long)(zbytes / ((size_t)DIM * 4));
    maxRows -= maxRows % 80;
    if (maxRows <= 0) maxRows = 80;
    if (maxRows > N_NODES) maxRows = N_NODES;

    k_detect<<<1,    256, 0, stream>>>((const unsigned short*)x, (const unsigned short*)W, ei, flags);
    k_init  <<<391,  256, 0, stream>>>(deg, stats);
    k_deg   <<<1250, 256, 0, stream>>>(ei, deg, flags);
    k_dinv  <<<391,  256, 0, stream>>>(deg, dinv);
    k_wt    <<<256,  256, 0, stream>>>(W, Wth, Wtl, flags);

    for (int base = 0; base < N_NODES; base += (int)maxRows) {
        int count = N_NODES - base;
        if (count > (int)maxRows) count = (int)maxRows;   // multiple of 80
        k_zinit  <<<count / 4, 256, 0, stream>>>(x, dinv, z, flags, base);
        k_scatter<<<80000,     256, 0, stream>>>(x, ei, dinv, z, flags, base, count);
        k_gemm   <<<count / 80, 256, 0, stream>>>(z, Wth, Wtl, out, base);
    }

    k_stats <<<1000,  256, 0, stream>>>(out, stats);
    k_fin   <<<1,     256, 0, stream>>>(stats, gamma, beta, scsh, flags);
    k_final <<<25000, 256, 0, stream>>>(out, scsh);
}

// Round 4
// 432.079 us; speedup vs baseline: 3.3207x; 3.3207x over previous
//
#include <hip/hip_runtime.h>
#include <stdint.h>

#define N_NODES 100000
#define N_EDGES 320000
#define DIM 256
#define BN_EPS 1e-5f

typedef __attribute__((ext_vector_type(8))) short short8;
typedef __attribute__((ext_vector_type(4))) float f32x4;

__device__ __forceinline__ float bf2f(unsigned short u) {
    union { unsigned int i; float f; } v; v.i = ((unsigned int)u) << 16; return v.f;
}
__device__ __forceinline__ unsigned short f2bf(float f) {
    union { float f; unsigned int i; } v; v.f = f;
    unsigned int x = v.i;
    return (unsigned short)((x + 0x7fffu + ((x >> 16) & 1u)) >> 16);  // RNE
}
__device__ __forceinline__ int eidx(const int* ei, int i64, int which, int e) {
    int idx = which * N_EDGES + e;
    return i64 ? ei[idx * 2] : ei[idx];
}
__device__ __forceinline__ f32x4 ldx4(const void* xv, int xf32, size_t off) {
    if (xf32) return *(const f32x4*)((const float*)xv + off);
    uint2 u = *(const uint2*)((const unsigned short*)xv + off);
    f32x4 o;
    o[0] = bf2f((unsigned short)(u.x & 0xffffu));
    o[1] = bf2f((unsigned short)(u.x >> 16));
    o[2] = bf2f((unsigned short)(u.y & 0xffffu));
    o[3] = bf2f((unsigned short)(u.y >> 16));
    return o;
}

// ---- runtime dtype detection (validated round 3) ----
__global__ void k_detect(const unsigned short* __restrict__ xs,
                         const unsigned short* __restrict__ wsw,
                         const int* __restrict__ ei, int* __restrict__ flags) {
    __shared__ int red[3];
    int tid = threadIdx.x;
    if (tid < 3) red[tid] = 0;
    __syncthreads();
    int badx = 0, badw = 0, nz = 0;
    for (int j = 0; j < 8; ++j) {
        if (!(fabsf(bf2f(xs[tid * 8 + j])) <= 1000.0f)) badx = 1;
        if (!(fabsf(bf2f(wsw[tid * 8 + j])) <= 1000.0f)) badw = 1;
        if (ei[(tid * 8 + j) * 2 + 1] != 0) nz = 1;
    }
    if (badx) atomicOr(&red[0], 1);
    if (badw) atomicOr(&red[1], 1);
    if (nz)   atomicOr(&red[2], 1);
    __syncthreads();
    if (tid == 0) { flags[0] = red[0]; flags[1] = red[1]; flags[2] = red[2] ? 0 : 1; }
}

__global__ void k_zero(int* __restrict__ cnt, float* __restrict__ stats) {
    int i = blockIdx.x * 256 + threadIdx.x;
    if (i < N_NODES) cnt[i] = 0;
    if (i < 512) stats[i] = 0.0f;
}

__global__ void k_cnt(const int* __restrict__ ei, int* __restrict__ cnt,
                      const int* __restrict__ flags) {
    int i64 = flags[2];
    int e = blockIdx.x * 256 + threadIdx.x;
    if (e < N_EDGES) atomicAdd(&cnt[eidx(ei, i64, 1, e)], 1);
}

__global__ void k_dinv(const int* __restrict__ cnt, float* __restrict__ dinv) {
    int i = blockIdx.x * 256 + threadIdx.x;
    if (i < N_NODES) dinv[i] = rsqrtf((float)cnt[i] + 1.0f);   // +1 self-loop
}

// ---- exclusive scan of cnt -> row_start (3 kernels; 200 chunks of 512) ----
__global__ void k_scan1(const int* __restrict__ cnt, int* __restrict__ partial) {
    __shared__ int red[256];
    int t = threadIdx.x, b = blockIdx.x;
    int i0 = b * 512 + t * 2;
    int s = 0;
    if (i0 < N_NODES) s += cnt[i0];
    if (i0 + 1 < N_NODES) s += cnt[i0 + 1];
    red[t] = s;
    __syncthreads();
    for (int off = 128; off > 0; off >>= 1) {
        if (t < off) red[t] += red[t + off];
        __syncthreads();
    }
    if (t == 0) partial[b] = red[0];
}

__global__ void k_scan2(const int* __restrict__ partial, int* __restrict__ pbase) {
    __shared__ int s[256];
    int t = threadIdx.x;
    int v = (t < 200) ? partial[t] : 0;
    s[t] = v;
    __syncthreads();
    for (int off = 1; off < 256; off <<= 1) {
        int u = (t >= off) ? s[t - off] : 0;
        __syncthreads();
        s[t] += u;
        __syncthreads();
    }
    if (t < 200) pbase[t] = s[t] - v;   // exclusive
}

__global__ void k_scan3(const int* __restrict__ cnt, const int* __restrict__ pbase,
                        int* __restrict__ row_start, int* __restrict__ cursor) {
    __shared__ int s[512];
    int t = threadIdx.x, b = blockIdx.x;
    int i = b * 512 + t;
    int v = (i < N_NODES) ? cnt[i] : 0;
    s[t] = v;
    __syncthreads();
    for (int off = 1; off < 512; off <<= 1) {
        int u = (t >= off) ? s[t - off] : 0;
        __syncthreads();
        s[t] += u;
        __syncthreads();
    }
    if (i < N_NODES) {
        int excl = pbase[b] + s[t] - v;
        row_start[i] = excl;
        cursor[i] = excl;
    }
}

// ---- CSR fill: slot per edge; store source idx + precomputed norm ----
__global__ void k_fill(const int* __restrict__ ei, const float* __restrict__ dinv,
                       int* __restrict__ cursor, int* __restrict__ csr_src,
                       float* __restrict__ csr_nrm, const int* __restrict__ flags) {
    int i64 = flags[2];
    int e = blockIdx.x * 256 + threadIdx.x;
    if (e >= N_EDGES) return;
    int c = eidx(ei, i64, 1, e);
    int r = eidx(ei, i64, 0, e);
    int slot = atomicAdd(&cursor[c], 1);
    csr_src[slot] = r;
    csr_nrm[slot] = dinv[r] * dinv[c];
}

// ---- W -> transposed split-bf16 (hi + lo) ----
__global__ void k_wt(const void* __restrict__ wv, unsigned short* __restrict__ Wth,
                     unsigned short* __restrict__ Wtl, const int* __restrict__ flags) {
    int wf32 = flags[1];
    int k = blockIdx.x, n = threadIdx.x;
    float v = wf32 ? ((const float*)wv)[k * DIM + n]
                   : bf2f(((const unsigned short*)wv)[k * DIM + n]);
    unsigned short h = f2bf(v);
    Wth[(size_t)n * DIM + k] = h;
    Wtl[(size_t)n * DIM + k] = f2bf(v - bf2f(h));
}

// ---- aggregation: one wave per node, register accumulate, single z write ----
__global__ void k_agg(const void* __restrict__ xv, const int* __restrict__ row_start,
                      const int* __restrict__ cnt, const int* __restrict__ csr_src,
                      const float* __restrict__ csr_nrm, const float* __restrict__ dinv,
                      float* __restrict__ z, const int* __restrict__ flags, int base) {
    int xf32 = flags[0];
    int gid = blockIdx.x * 256 + threadIdx.x;   // count*64 threads
    int node = base + (gid >> 6);
    int lane = gid & 63;
    float dv = dinv[node];
    float s = dv * dv;
    f32x4 acc = ldx4(xv, xf32, (size_t)node * DIM + lane * 4);
    acc[0] *= s; acc[1] *= s; acc[2] *= s; acc[3] *= s;
    int start = row_start[node];
    int len = cnt[node];                         // wave-uniform loop
    for (int j = 0; j < len; ++j) {
        int src = csr_src[start + j];            // broadcast load (L2-resident)
        float nrm = csr_nrm[start + j];
        f32x4 xr = ldx4(xv, xf32, (size_t)src * DIM + lane * 4);
        acc[0] += nrm * xr[0]; acc[1] += nrm * xr[1];
        acc[2] += nrm * xr[2]; acc[3] += nrm * xr[3];
    }
    *(f32x4*)(z + (size_t)(node - base) * DIM + lane * 4) = acc;
}

// ---- GEMM: out = z @ W (split-bf16, 3 MFMAs), M-tile 80, fused BN-stats epilogue ----
__launch_bounds__(256)
__global__ void k_gemm(const float* __restrict__ z, const unsigned short* __restrict__ Wth,
                       const unsigned short* __restrict__ Wtl, float* __restrict__ out,
                       float* __restrict__ stats, int base) {
    __shared__ unsigned short zh[80][264];
    __shared__ unsigned short zl[80][264];
    __shared__ float bs[512];
    int tid = threadIdx.x;
    int m0l = blockIdx.x * 80;
    {
        int rr = tid >> 4;
        int c0 = (tid & 15) * 16;
        if (tid < 256) { bs[tid] = 0.0f; bs[tid + 256] = 0.0f; }
        #pragma unroll
        for (int p = 0; p < 5; ++p) {
            int r = p * 16 + rr;
            const float* src = z + (size_t)(m0l + r) * DIM + c0;
            #pragma unroll
            for (int half = 0; half < 2; ++half) {
                short8 ph, pl;
                #pragma unroll
                for (int j4 = 0; j4 < 8; j4 += 4) {
                    f32x4 t = *(const f32x4*)(src + half * 8 + j4);
                    #pragma unroll
                    for (int j = 0; j < 4; ++j) {
                        float v = t[j];
                        unsigned short h = f2bf(v);
                        ph[j4 + j] = (short)h;
                        pl[j4 + j] = (short)f2bf(v - bf2f(h));
                    }
                }
                *(short8*)&zh[r][c0 + half * 8] = ph;
                *(short8*)&zl[r][c0 + half * 8] = pl;
            }
        }
    }
    __syncthreads();
    int w = tid >> 6, lane = tid & 63, quad = lane >> 4, rl = lane & 15;
    f32x4 acc[5][4];
    #pragma unroll
    for (int ms = 0; ms < 5; ++ms)
        #pragma unroll
        for (int nt = 0; nt < 4; ++nt)
            acc[ms][nt] = (f32x4){0.f, 0.f, 0.f, 0.f};
    #pragma unroll
    for (int kk = 0; kk < 8; ++kk) {
        int k0 = kk * 32 + quad * 8;
        short8 bh[4], bl[4];
        #pragma unroll
        for (int nt = 0; nt < 4; ++nt) {
            int n = w * 64 + nt * 16 + rl;
            bh[nt] = *(const short8*)(Wth + (size_t)n * DIM + k0);
            bl[nt] = *(const short8*)(Wtl + (size_t)n * DIM + k0);
        }
        #pragma unroll
        for (int ms = 0; ms < 5; ++ms) {
            short8 ah = *(const short8*)&zh[ms * 16 + rl][k0];
            short8 al = *(const short8*)&zl[ms * 16 + rl][k0];
            #pragma unroll
            for (int nt = 0; nt < 4; ++nt) {
                acc[ms][nt] = __builtin_amdgcn_mfma_f32_16x16x32_bf16(ah, bh[nt], acc[ms][nt], 0, 0, 0);
                acc[ms][nt] = __builtin_amdgcn_mfma_f32_16x16x32_bf16(al, bh[nt], acc[ms][nt], 0, 0, 0);
                acc[ms][nt] = __builtin_amdgcn_mfma_f32_16x16x32_bf16(ah, bl[nt], acc[ms][nt], 0, 0, 0);
            }
        }
    }
    // C/D layout: col = lane&15 (n), row = quad*4 + reg (m)
    #pragma unroll
    for (int nt = 0; nt < 4; ++nt) {
        int col = w * 64 + nt * 16 + rl;
        float s1 = 0.f, s2 = 0.f;
        #pragma unroll
        for (int ms = 0; ms < 5; ++ms)
            #pragma unroll
            for (int i = 0; i < 4; ++i) {
                float v = acc[ms][nt][i];
                s1 += v; s2 += v * v;
                out[(size_t)(base + m0l + ms * 16 + quad * 4 + i) * DIM + col] = v;
            }
        atomicAdd(&bs[col], s1);
        atomicAdd(&bs[256 + col], s2);
    }
    __syncthreads();
    if (tid < 256) {
        atomicAdd(&stats[tid], bs[tid]);
        atomicAdd(&stats[256 + tid], bs[256 + tid]);
    }
}

// ---- fold BN into per-column scale/shift ----
__global__ void k_fin(const float* __restrict__ stats, const void* __restrict__ gv,
                      const void* __restrict__ bv, float* __restrict__ scsh,
                      const int* __restrict__ flags) {
    int ff32 = flags[0];
    int f = threadIdx.x;
    const float invN = 1.0f / (float)N_NODES;
    float mean = stats[f] * invN;
    float var = stats[256 + f] * invN - mean * mean;
    float g = ff32 ? ((const float*)gv)[f] : bf2f(((const unsigned short*)gv)[f]);
    float bb = ff32 ? ((const float*)bv)[f] : bf2f(((const unsigned short*)bv)[f]);
    float sc = g * rsqrtf(var + BN_EPS);
    scsh[f] = sc;
    scsh[256 + f] = bb - mean * sc;
}

// ---- fused normalize + tanh, in place on fp32 d_out ----
__global__ void k_final(float* __restrict__ out, const float* __restrict__ scsh) {
    int t = blockIdx.x * 256 + threadIdx.x;
    int f0 = (t & 63) * 4;
    size_t off = (size_t)t * 4;
    f32x4 v = *(const f32x4*)(out + off);
    f32x4 o;
    #pragma unroll
    for (int j = 0; j < 4; ++j)
        o[j] = tanhf(v[j] * scsh[f0 + j] + scsh[256 + f0 + j]);
    *(f32x4*)(out + off) = o;
}

extern "C" void kernel_launch(void* const* d_in, const int* in_sizes, int n_in,
                              void* d_out, int out_size, void* d_ws, size_t ws_size,
                              hipStream_t stream) {
    const void* x     = d_in[0];
    const void* W     = d_in[1];
    // d_in[2] = b: additive per-column constant, cancelled exactly by BatchNorm. Unused.
    const void* gamma = d_in[3];
    const void* beta  = d_in[4];
    const int* ei     = (const int*)d_in[5];
    float* out = (float*)d_out;   // fp32 output (validated round 3)

    char* ws = (char*)d_ws;
    int*   flags     = (int*)(ws);
    int*   cnt       = (int*)(ws + 4096);
    int*   row_start = (int*)(ws + 409600);
    int*   cursor    = (int*)(ws + 819200);
    float* dinv      = (float*)(ws + 1228800);
    int*   partial   = (int*)(ws + 1638400);
    int*   pbase     = (int*)(ws + 1646592);
    float* stats     = (float*)(ws + 1654784);
    float* scsh      = (float*)(ws + 1662976);
    unsigned short* Wth = (unsigned short*)(ws + 1671168);
    unsigned short* Wtl = (unsigned short*)(ws + 1802240);
    int*   csr_src   = (int*)(ws + 1933312);
    float* csr_nrm   = (float*)(ws + 3215360);
    const size_t zoff = 4718592;
    float* z         = (float*)(ws + zoff);

    // ws-adaptive chunking of the fp32 z buffer (host-side branch: constant across calls)
    size_t zbytes = ws_size > zoff ? ws_size - zoff : 0;
    long long maxRows = (long long)(zbytes / ((size_t)DIM * 4));
    maxRows -= maxRows % 80;
    if (maxRows <= 0) maxRows = 80;
    if (maxRows > N_NODES) maxRows = N_NODES;

    k_detect<<<1,    256, 0, stream>>>((const unsigned short*)x, (const unsigned short*)W, ei, flags);
    k_zero  <<<391,  256, 0, stream>>>(cnt, stats);
    k_cnt   <<<1250, 256, 0, stream>>>(ei, cnt, flags);
    k_dinv  <<<391,  256, 0, stream>>>(cnt, dinv);
    k_scan1 <<<200,  256, 0, stream>>>(cnt, partial);
    k_scan2 <<<1,    256, 0, stream>>>(partial, pbase);
    k_scan3 <<<200,  512, 0, stream>>>(cnt, pbase, row_start, cursor);
    k_fill  <<<1250, 256, 0, stream>>>(ei, dinv, cursor, csr_src, csr_nrm, flags);
    k_wt    <<<256,  256, 0, stream>>>(W, Wth, Wtl, flags);

    for (int base = 0; base < N_NODES; base += (int)maxRows) {
        int count = N_NODES - base;
        if (count > (int)maxRows) count = (int)maxRows;   // multiple of 80
        k_agg <<<count / 4,  256, 0, stream>>>(x, row_start, cnt, csr_src, csr_nrm,
                                               dinv, z, flags, base);
        k_gemm<<<count / 80, 256, 0, stream>>>(z, Wth, Wtl, out, stats, base);
    }

    k_fin  <<<1,     256, 0, stream>>>(stats, gamma, beta, scsh, flags);
    k_final<<<25000, 256, 0, stream>>>(out, scsh);
}